// Round 1
// baseline (371.356 us; speedup 1.0000x reference)
//
#include <hip/hip_runtime.h>
#include <math.h>

#define TILE 64

// One block per 64x64 output tile in the upper triangle (incl. diagonal).
// Strictly-upper tiles: coalesced comp load -> aligned float4 upper store +
// LDS-transposed aligned float4 lower store. Diagonal tiles: scalar predicated.
__global__ __launch_bounds__(256) void uncompress_sym_kernel(
    const float* __restrict__ comp, float* __restrict__ out, int n) {
    const int tr = blockIdx.y;   // tile row
    const int tc = blockIdx.x;   // tile col
    if (tc < tr) return;         // lower tiles handled by their mirror block

    const int tid = threadIdx.x;
    __shared__ float s[TILE][TILE + 1];  // +1: odd stride -> conflict-free transpose

    const int i0 = tr * TILE;
    const int j0 = tc * TILE;

    if (tr == tc) {
        // Diagonal tile: strict upper from comp, diag = 1, lower mirrored in-tile.
        for (int e = tid; e < TILE * TILE; e += 256) {
            const int y = e >> 6;
            const int x = e & 63;
            float v = 0.0f;
            if (x > y) {
                const int i = i0 + y;
                const int j = j0 + x;
                // idx(i,j) = i*(2n-i-1)/2 + (j-i-1), i<j
                const int base = i * (2 * n - i - 1) / 2 - i - 1;
                v = comp[base + j];
            }
            s[y][x] = v;
        }
        __syncthreads();
        for (int e = tid; e < TILE * TILE; e += 256) {
            const int y = e >> 6;
            const int x = e & 63;
            float v;
            if (x > y)      v = s[y][x];
            else if (x == y) v = 1.0f;
            else            v = s[x][y];
            out[(size_t)(i0 + y) * n + (j0 + x)] = v;
        }
    } else {
        // Strictly-upper tile. Each wave covers 4 rows; lanes 0-15 cover one
        // contiguous 64-float row segment (float4 per lane).
        for (int it = 0; it < 4; ++it) {
            const int y  = (tid >> 4) + it * 16;
            const int x4 = (tid & 15) * 4;
            const int i  = i0 + y;
            const int base = i * (2 * n - i - 1) / 2 - i - 1;  // comp idx = base + j
            float4 v;
            __builtin_memcpy(&v, &comp[base + j0 + x4], sizeof(float4));  // 4B-aligned source
            *(float4*)&out[(size_t)i * n + (j0 + x4)] = v;  // 16B-aligned
            s[y][x4 + 0] = v.x;
            s[y][x4 + 1] = v.y;
            s[y][x4 + 2] = v.z;
            s[y][x4 + 3] = v.w;
        }
        __syncthreads();
        // Mirrored lower tile (tile-row j, tile-col i): out[j][i] = s[i-i0][j-j0].
        for (int it = 0; it < 4; ++it) {
            const int y  = (tid >> 4) + it * 16;
            const int x4 = (tid & 15) * 4;
            float4 w;
            w.x = s[x4 + 0][y];  // stride-65 LDS reads: bank = (x4+k+y)%32, 2-way max (free)
            w.y = s[x4 + 1][y];
            w.z = s[x4 + 2][y];
            w.w = s[x4 + 3][y];
            *(float4*)&out[(size_t)(j0 + y) * n + (i0 + x4)] = w;  // 16B-aligned
        }
    }
}

extern "C" void kernel_launch(void* const* d_in, const int* in_sizes, int n_in,
                              void* d_out, int out_size, void* d_ws, size_t ws_size,
                              hipStream_t stream) {
    const float* comp = (const float*)d_in[0];
    float* out = (float*)d_out;
    const long long m = in_sizes[0];
    const int n = (int)llround(sqrt(2.0 * (double)m)) + 1;  // 8192
    const int T = n / TILE;                                 // 128 (n % 64 == 0)
    dim3 grid(T, T);
    uncompress_sym_kernel<<<grid, 256, 0, stream>>>(comp, out, n);
}